// Round 1
// baseline (293.562 us; speedup 1.0000x reference)
//
#include <hip/hip_runtime.h>

// bf16 MFMA fragment types per cdna_hip_programming.md §3 (compile-verified on gfx950)
typedef __attribute__((ext_vector_type(8))) short bf16x8;   // 8 bf16 = 4 VGPRs
typedef __attribute__((ext_vector_type(4))) float f32x4;    // 4 fp32 accum
typedef __attribute__((ext_vector_type(4))) unsigned int u32x4;

#define LDSTR 136            // 128 + 8 bf16 pad (16 B) -> rows alias 2-way max (free)
#define TILES_PER_WAVE 8     // 8 * 16 = 128 edges per wave; 512 per block

// f32 -> bf16 round-to-nearest-even, two at a time packed into one dword
static __device__ __forceinline__ unsigned int pack2bf(float x, float y) {
  unsigned int ux = __builtin_bit_cast(unsigned int, x);
  ux += 0x7fffu + ((ux >> 16) & 1u);
  unsigned int uy = __builtin_bit_cast(unsigned int, y);
  uy += 0x7fffu + ((uy >> 16) & 1u);
  return (ux >> 16) | (uy & 0xffff0000u);
}

static __device__ __forceinline__ unsigned short f2bf_s(float x) {
  unsigned int ux = __builtin_bit_cast(unsigned int, x);
  ux += 0x7fffu + ((ux >> 16) & 1u);
  return (unsigned short)(ux >> 16);
}

static __device__ __forceinline__ bf16x8 make_afrag(float4 lo, float4 hi) {
  u32x4 p;
  p[0] = pack2bf(lo.x, lo.y);
  p[1] = pack2bf(lo.z, lo.w);
  p[2] = pack2bf(hi.x, hi.y);
  p[3] = pack2bf(hi.z, hi.w);
  return __builtin_bit_cast(bf16x8, p);
}

__global__ __launch_bounds__(256) void edge_mlp(
    const float* __restrict__ nodes_emb,   // [150000, 64]
    const int*   __restrict__ src,         // [E]
    const int*   __restrict__ dst,         // [E]
    const float* __restrict__ W1,          // [128, 64] row-major
    const float* __restrict__ b1,          // [64]
    const float* __restrict__ W2,          // [64, 1]
    const float* __restrict__ b2,          // [1]
    float*       __restrict__ out,         // [E, 1]
    int E)
{
  __shared__ unsigned short ls_w1t[64 * LDSTR];  // W1 transposed: [n][k], bf16
  __shared__ float ls_b1[64];
  __shared__ float ls_w2[64];

  const int tid  = threadIdx.x;
  const int wave = tid >> 6;
  const int lane = tid & 63;
  const int l15  = lane & 15;
  const int quad = lane >> 4;

  // Stage W1^T (bf16) + b1 + W2 into LDS (once per block; W1 is 32 KB, L2-hot)
  for (int i = tid; i < 64 * 128; i += 256) {
    int n = i >> 7;      // output channel
    int k = i & 127;     // input channel
    ls_w1t[n * LDSTR + k] = f2bf_s(W1[k * 64 + n]);
  }
  if (tid < 64) { ls_b1[tid] = b1[tid]; ls_w2[tid] = W2[tid]; }
  __syncthreads();

  // Hoist all B fragments to registers: bfrag[tn][s] covers
  // B[k = s*32 + quad*8 + j][n = tn*16 + l15]  (B-layout: n=lane&15, k=quad*8+j)
  bf16x8 bfrag[4][4];
  #pragma unroll
  for (int tn = 0; tn < 4; ++tn)
    #pragma unroll
    for (int s = 0; s < 4; ++s)
      bfrag[tn][s] = *(const bf16x8*)&ls_w1t[(tn * 16 + l15) * LDSTR + s * 32 + quad * 8];

  float myb1[4], myw2[4];
  #pragma unroll
  for (int tn = 0; tn < 4; ++tn) {
    myb1[tn] = ls_b1[tn * 16 + l15];
    myw2[tn] = ls_w2[tn * 16 + l15];
  }
  const float b2v = b2[0];

  const int wave_base = blockIdx.x * (TILES_PER_WAVE * 64) + wave * (TILES_PER_WAVE * 16);

  #pragma unroll 1
  for (int t = 0; t < TILES_PER_WAVE; ++t) {
    const int tile_base = wave_base + t * 16;
    if (tile_base >= E) break;          // E % 16 == 0, so active tiles are full

    // Gather: lane (l15, quad) loads the 8-float slivers of edge l15's
    // src/dst rows that form its A-fragment elements directly. No LDS.
    const int e  = tile_base + l15;
    const int si = src[e];
    const int di = dst[e];
    const float* srow = nodes_emb + (long long)si * 64 + quad * 8;
    const float* drow = nodes_emb + (long long)di * 64 + quad * 8;

    float4 v0 = *(const float4*)(srow);        // src k: quad*8 .. +7
    float4 v1 = *(const float4*)(srow + 4);
    float4 v2 = *(const float4*)(srow + 32);   // src k: 32+quad*8 .. +7
    float4 v3 = *(const float4*)(srow + 36);
    float4 v4 = *(const float4*)(drow);        // dst k: quad*8 .. +7
    float4 v5 = *(const float4*)(drow + 4);
    float4 v6 = *(const float4*)(drow + 32);   // dst k: 32+quad*8 .. +7
    float4 v7 = *(const float4*)(drow + 36);

    bf16x8 afr[4];
    afr[0] = make_afrag(v0, v1);
    afr[1] = make_afrag(v2, v3);
    afr[2] = make_afrag(v4, v5);
    afr[3] = make_afrag(v6, v7);

    f32x4 acc[4];
    #pragma unroll
    for (int tn = 0; tn < 4; ++tn) acc[tn] = (f32x4){0.f, 0.f, 0.f, 0.f};

    #pragma unroll
    for (int s = 0; s < 4; ++s)
      #pragma unroll
      for (int tn = 0; tn < 4; ++tn)
        acc[tn] = __builtin_amdgcn_mfma_f32_16x16x32_bf16(afr[s], bfrag[tn][s], acc[tn], 0, 0, 0);

    // Layer 2 in fp32: D layout col = l15 (channel), row = quad*4 + r (edge)
    #pragma unroll
    for (int r = 0; r < 4; ++r) {
      float p = 0.f;
      #pragma unroll
      for (int tn = 0; tn < 4; ++tn) {
        float h = acc[tn][r] + myb1[tn];
        h = fmaxf(h, 0.f);
        p = __builtin_fmaf(h, myw2[tn], p);
      }
      // reduce the 16 channel-lanes of this quad
      p += __shfl_xor(p, 1);
      p += __shfl_xor(p, 2);
      p += __shfl_xor(p, 4);
      p += __shfl_xor(p, 8);
      if (l15 == 0) out[tile_base + quad * 4 + r] = p + b2v;
    }
  }
}

extern "C" void kernel_launch(void* const* d_in, const int* in_sizes, int n_in,
                              void* d_out, int out_size, void* d_ws, size_t ws_size,
                              hipStream_t stream) {
  const float* nodes_emb = (const float*)d_in[0];
  const int*   src       = (const int*)d_in[1];
  const int*   dst       = (const int*)d_in[2];
  const float* W1        = (const float*)d_in[3];
  const float* b1        = (const float*)d_in[4];
  const float* W2        = (const float*)d_in[5];
  const float* b2        = (const float*)d_in[6];
  float* out = (float*)d_out;

  const int E = in_sizes[1];                    // 2,000,000
  const int epb = TILES_PER_WAVE * 64;          // 512 edges per block
  const int blocks = (E + epb - 1) / epb;

  hipLaunchKernelGGL(edge_mlp, dim3(blocks), dim3(256), 0, stream,
                     nodes_emb, src, dst, W1, b1, W2, b2, out, E);
}

// Round 2
// 226.225 us; speedup vs baseline: 1.2977x; 1.2977x over previous
//
#include <hip/hip_runtime.h>

// bf16 MFMA fragment types (gfx950): A/B = 8 bf16 (4 VGPR), C/D = 4 fp32
typedef __attribute__((ext_vector_type(8))) short bf16x8;
typedef __attribute__((ext_vector_type(4))) float f32x4;
typedef __attribute__((ext_vector_type(2))) unsigned int u32x2;
typedef __attribute__((ext_vector_type(4))) unsigned int u32x4;

#define LDSTR 136            // W1^T LDS leading dim (shorts): 128 + 8 pad
#define TPW 8                // 16-edge tiles per wave; 512 edges per block

// f32 -> bf16 round-to-nearest-even
static __device__ __forceinline__ unsigned int pack2bf(float x, float y) {
  unsigned int ux = __builtin_bit_cast(unsigned int, x);
  ux += 0x7fffu + ((ux >> 16) & 1u);
  unsigned int uy = __builtin_bit_cast(unsigned int, y);
  uy += 0x7fffu + ((uy >> 16) & 1u);
  return (ux >> 16) | (uy & 0xffff0000u);
}
static __device__ __forceinline__ unsigned short f2bf_s(float x) {
  unsigned int ux = __builtin_bit_cast(unsigned int, x);
  ux += 0x7fffu + ((ux >> 16) & 1u);
  return (unsigned short)(ux >> 16);
}

// ---- pass 0: node table f32 -> bf16 into d_ws (row = 128 B = 1 cache line) ----
__global__ __launch_bounds__(256) void cvt_nodes(const float4* __restrict__ in,
                                                 u32x2* __restrict__ out, int n4) {
  int i = blockIdx.x * 256 + threadIdx.x;
  if (i < n4) {
    float4 v = in[i];
    u32x2 p;
    p[0] = pack2bf(v.x, v.y);
    p[1] = pack2bf(v.z, v.w);
    out[i] = p;
  }
}

// ---- main: gather bf16 rows directly into A-fragments, MFMA MLP ----
__global__ __launch_bounds__(256) void edge_mlp_bf16(
    const unsigned short* __restrict__ nodes_bf,  // [N,64] bf16
    const int*   __restrict__ src,
    const int*   __restrict__ dst,
    const float* __restrict__ W1,   // [128,64] f32 row-major
    const float* __restrict__ b1,
    const float* __restrict__ W2,   // [64]
    const float* __restrict__ b2,
    float*       __restrict__ out,  // [E]
    int E)
{
  __shared__ unsigned short ls_w1t[64 * LDSTR];
  __shared__ float ls_b1[64];
  __shared__ float ls_w2[64];

  const int tid  = threadIdx.x;
  const int wave = tid >> 6;
  const int lane = tid & 63;
  const int l15  = lane & 15;
  const int quad = lane >> 4;

  for (int i = tid; i < 64 * 128; i += 256) {
    int n = i >> 7, k = i & 127;
    ls_w1t[n * LDSTR + k] = f2bf_s(W1[k * 64 + n]);
  }
  if (tid < 64) { ls_b1[tid] = b1[tid]; ls_w2[tid] = W2[tid]; }
  __syncthreads();

  // B fragments: bfrag[tn][s] = W1T[n=tn*16+l15][k=s*32+quad*8 .. +7]
  bf16x8 bfrag[4][4];
  #pragma unroll
  for (int tn = 0; tn < 4; ++tn)
    #pragma unroll
    for (int s = 0; s < 4; ++s)
      bfrag[tn][s] = *(const bf16x8*)&ls_w1t[(tn * 16 + l15) * LDSTR + s * 32 + quad * 8];

  float myb1[4], myw2[4];
  #pragma unroll
  for (int tn = 0; tn < 4; ++tn) {
    myb1[tn] = ls_b1[tn * 16 + l15];
    myw2[tn] = ls_w2[tn * 16 + l15];
  }
  const float b2v = b2[0];

  const int wave_base = blockIdx.x * (TPW * 64) + wave * (TPW * 16);

  // Preload all tile indices (coalesced, L2-hot). Clamp for overshoot tiles.
  int sis[TPW], dis[TPW];
  #pragma unroll
  for (int t = 0; t < TPW; ++t) {
    int e = wave_base + t * 16 + l15;
    e = (e < E) ? e : 0;
    sis[t] = src[e];
    dis[t] = dst[e];
  }

  // Row gathers: lane (l15,quad) loads the two 16-B slivers of edge l15's
  // src/dst bf16 rows that ARE its A-fragments (no repack, no LDS).
  bf16x8 c0, c1, c2, c3;
  {
    const unsigned short* sr = nodes_bf + (long long)sis[0] * 64 + quad * 8;
    const unsigned short* dr = nodes_bf + (long long)dis[0] * 64 + quad * 8;
    c0 = *(const bf16x8*)(sr);       // src k  0..31 sliver
    c1 = *(const bf16x8*)(sr + 32);  // src k 32..63 sliver
    c2 = *(const bf16x8*)(dr);       // dst k  0..31
    c3 = *(const bf16x8*)(dr + 32);  // dst k 32..63
  }

  #pragma unroll
  for (int t = 0; t < TPW; ++t) {
    // Prefetch tile t+1 before computing tile t
    bf16x8 n0 = c0, n1 = c1, n2 = c2, n3 = c3;
    if (t + 1 < TPW) {
      const unsigned short* sr = nodes_bf + (long long)sis[t + 1] * 64 + quad * 8;
      const unsigned short* dr = nodes_bf + (long long)dis[t + 1] * 64 + quad * 8;
      n0 = *(const bf16x8*)(sr);
      n1 = *(const bf16x8*)(sr + 32);
      n2 = *(const bf16x8*)(dr);
      n3 = *(const bf16x8*)(dr + 32);
    }

    const int tile_base = wave_base + t * 16;
    if (tile_base < E) {
      f32x4 acc[4];
      #pragma unroll
      for (int tn = 0; tn < 4; ++tn) acc[tn] = (f32x4){0.f, 0.f, 0.f, 0.f};

      #pragma unroll
      for (int tn = 0; tn < 4; ++tn) {
        acc[tn] = __builtin_amdgcn_mfma_f32_16x16x32_bf16(c0, bfrag[tn][0], acc[tn], 0, 0, 0);
        acc[tn] = __builtin_amdgcn_mfma_f32_16x16x32_bf16(c1, bfrag[tn][1], acc[tn], 0, 0, 0);
        acc[tn] = __builtin_amdgcn_mfma_f32_16x16x32_bf16(c2, bfrag[tn][2], acc[tn], 0, 0, 0);
        acc[tn] = __builtin_amdgcn_mfma_f32_16x16x32_bf16(c3, bfrag[tn][3], acc[tn], 0, 0, 0);
      }

      // Layer 2: D layout col=l15 (channel n), row=quad*4+r (edge)
      #pragma unroll
      for (int r = 0; r < 4; ++r) {
        float p = 0.f;
        #pragma unroll
        for (int tn = 0; tn < 4; ++tn) {
          float h = acc[tn][r] + myb1[tn];
          h = fmaxf(h, 0.f);
          p = __builtin_fmaf(h, myw2[tn], p);
        }
        p += __shfl_xor(p, 1);
        p += __shfl_xor(p, 2);
        p += __shfl_xor(p, 4);
        p += __shfl_xor(p, 8);
        if (l15 == 0) out[tile_base + quad * 4 + r] = p + b2v;
      }
    }
    c0 = n0; c1 = n1; c2 = n2; c3 = n3;
  }
}

// ---- fallback (round-1 kernel, f32 gathers) if ws too small for bf16 table ----
typedef __attribute__((ext_vector_type(4))) unsigned int u32x4f;
static __device__ __forceinline__ bf16x8 make_afrag(float4 lo, float4 hi) {
  u32x4 p;
  p[0] = pack2bf(lo.x, lo.y);
  p[1] = pack2bf(lo.z, lo.w);
  p[2] = pack2bf(hi.x, hi.y);
  p[3] = pack2bf(hi.z, hi.w);
  return __builtin_bit_cast(bf16x8, p);
}

__global__ __launch_bounds__(256) void edge_mlp_f32(
    const float* __restrict__ nodes_emb, const int* __restrict__ src,
    const int* __restrict__ dst, const float* __restrict__ W1,
    const float* __restrict__ b1, const float* __restrict__ W2,
    const float* __restrict__ b2, float* __restrict__ out, int E)
{
  __shared__ unsigned short ls_w1t[64 * LDSTR];
  __shared__ float ls_b1[64];
  __shared__ float ls_w2[64];
  const int tid = threadIdx.x, wave = tid >> 6, lane = tid & 63;
  const int l15 = lane & 15, quad = lane >> 4;
  for (int i = tid; i < 64 * 128; i += 256) {
    int n = i >> 7, k = i & 127;
    ls_w1t[n * LDSTR + k] = f2bf_s(W1[k * 64 + n]);
  }
  if (tid < 64) { ls_b1[tid] = b1[tid]; ls_w2[tid] = W2[tid]; }
  __syncthreads();
  bf16x8 bfrag[4][4];
  #pragma unroll
  for (int tn = 0; tn < 4; ++tn)
    #pragma unroll
    for (int s = 0; s < 4; ++s)
      bfrag[tn][s] = *(const bf16x8*)&ls_w1t[(tn * 16 + l15) * LDSTR + s * 32 + quad * 8];
  float myb1[4], myw2[4];
  #pragma unroll
  for (int tn = 0; tn < 4; ++tn) { myb1[tn] = ls_b1[tn*16+l15]; myw2[tn] = ls_w2[tn*16+l15]; }
  const float b2v = b2[0];
  const int wave_base = blockIdx.x * (TPW * 64) + wave * (TPW * 16);
  #pragma unroll 1
  for (int t = 0; t < TPW; ++t) {
    const int tile_base = wave_base + t * 16;
    if (tile_base >= E) break;
    const int e = tile_base + l15;
    const int si = src[e], di = dst[e];
    const float* srow = nodes_emb + (long long)si * 64 + quad * 8;
    const float* drow = nodes_emb + (long long)di * 64 + quad * 8;
    float4 v0 = *(const float4*)(srow),      v1 = *(const float4*)(srow + 4);
    float4 v2 = *(const float4*)(srow + 32), v3 = *(const float4*)(srow + 36);
    float4 v4 = *(const float4*)(drow),      v5 = *(const float4*)(drow + 4);
    float4 v6 = *(const float4*)(drow + 32), v7 = *(const float4*)(drow + 36);
    bf16x8 afr[4] = {make_afrag(v0,v1), make_afrag(v2,v3), make_afrag(v4,v5), make_afrag(v6,v7)};
    f32x4 acc[4];
    #pragma unroll
    for (int tn = 0; tn < 4; ++tn) acc[tn] = (f32x4){0.f,0.f,0.f,0.f};
    #pragma unroll
    for (int s = 0; s < 4; ++s)
      #pragma unroll
      for (int tn = 0; tn < 4; ++tn)
        acc[tn] = __builtin_amdgcn_mfma_f32_16x16x32_bf16(afr[s], bfrag[tn][s], acc[tn], 0, 0, 0);
    #pragma unroll
    for (int r = 0; r < 4; ++r) {
      float p = 0.f;
      #pragma unroll
      for (int tn = 0; tn < 4; ++tn) {
        float h = acc[tn][r] + myb1[tn];
        h = fmaxf(h, 0.f);
        p = __builtin_fmaf(h, myw2[tn], p);
      }
      p += __shfl_xor(p, 1); p += __shfl_xor(p, 2);
      p += __shfl_xor(p, 4); p += __shfl_xor(p, 8);
      if (l15 == 0) out[tile_base + quad * 4 + r] = p + b2v;
    }
  }
}

extern "C" void kernel_launch(void* const* d_in, const int* in_sizes, int n_in,
                              void* d_out, int out_size, void* d_ws, size_t ws_size,
                              hipStream_t stream) {
  const float* nodes_emb = (const float*)d_in[0];
  const int*   src       = (const int*)d_in[1];
  const int*   dst       = (const int*)d_in[2];
  const float* W1        = (const float*)d_in[3];
  const float* b1        = (const float*)d_in[4];
  const float* W2        = (const float*)d_in[5];
  const float* b2        = (const float*)d_in[6];
  float* out = (float*)d_out;

  const int E = in_sizes[1];
  const int nodes_elems = in_sizes[0];               // 150000*64
  const int epb = TPW * 64;                          // 512 edges / block
  const int blocks = (E + epb - 1) / epb;
  const size_t need = (size_t)nodes_elems * 2;       // bf16 table bytes

  if (ws_size >= need) {
    const int n4 = nodes_elems / 4;
    hipLaunchKernelGGL(cvt_nodes, dim3((n4 + 255) / 256), dim3(256), 0, stream,
                       (const float4*)nodes_emb, (u32x2*)d_ws, n4);
    hipLaunchKernelGGL(edge_mlp_bf16, dim3(blocks), dim3(256), 0, stream,
                       (const unsigned short*)d_ws, src, dst, W1, b1, W2, b2, out, E);
  } else {
    hipLaunchKernelGGL(edge_mlp_f32, dim3(blocks), dim3(256), 0, stream,
                       nodes_emb, src, dst, W1, b1, W2, b2, out, E);
  }
}